// Round 2
// baseline (451.913 us; speedup 1.0000x reference)
//
#include <hip/hip_runtime.h>

#define IMG_H 256
#define IMG_W 256
#define ROWS_PER_WAVE 64
#define STRIPS 4   // IMG_H / ROWS_PER_WAVE
#define N_IMG 1024 // 16*64

typedef float v4f __attribute__((ext_vector_type(4)));

__device__ __forceinline__ float4 fmax4(const float4 a, const float4 b) {
    return make_float4(fmaxf(a.x, b.x), fmaxf(a.y, b.y), fmaxf(a.z, b.z), fmaxf(a.w, b.w));
}

// Fused hex maxpool: out[h][w] = max over hex window (19 taps), OOB -> 0.0
// w even: col w rows h-2..h+2 ; cols w+-1 rows h-2..h+1 ; cols w+-2 rows h-1..h+1
// w odd : col w rows h-2..h+2 ; cols w+-1 rows h-1..h+2 ; cols w+-2 rows h-1..h+1
__global__ __launch_bounds__(256) void hex_maxpool_kernel(const float* __restrict__ in,
                                                          float* __restrict__ out) {
    const int lane  = threadIdx.x & 63;
    const int wave  = threadIdx.x >> 6;
    const int gw    = blockIdx.x * 4 + wave;      // global wave id, 0..4095
    const int img   = gw >> 2;                    // 0..1023
    const int strip = gw & 3;                     // 0..3
    const int h0    = strip * ROWS_PER_WAVE;
    const int col   = lane * 4;                   // 64 lanes * 4 = 256 = full row

    const float* p = in  + (size_t)img * (IMG_H * IMG_W);
    float*       q = out + (size_t)img * (IMG_H * IMG_W);

    auto load_row = [&](int r) -> float4 {
        if ((unsigned)r < (unsigned)IMG_H) {
            return *reinterpret_cast<const float4*>(p + r * IMG_W + col);
        }
        return make_float4(0.f, 0.f, 0.f, 0.f);
    };

    // one output row from its 5 input rows (h-2..h+2)
    auto hexrow = [&](const float4 w0, const float4 w1, const float4 w2,
                      const float4 w3, const float4 w4) -> float4 {
        const float4 m3 = fmax4(fmax4(w1, w2), w3); // rows h-1..h+1
        const float4 bu = fmax4(m3, w0);            // rows h-2..h+1
        const float4 bd = fmax4(m3, w4);            // rows h-1..h+2
        const float4 a5 = fmax4(bu, w4);            // rows h-2..h+2

        float Lbuw = __shfl_up(bu.w, 1);
        float Lm3z = __shfl_up(m3.z, 1);
        float Lm3w = __shfl_up(m3.w, 1);
        float Rbdx = __shfl_down(bd.x, 1);
        float Rm3x = __shfl_down(m3.x, 1);
        float Rm3y = __shfl_down(m3.y, 1);
        if (lane == 0)  { Lbuw = 0.f; Lm3z = 0.f; Lm3w = 0.f; }  // cols -1,-2 pad(0)
        if (lane == 63) { Rbdx = 0.f; Rm3x = 0.f; Rm3y = 0.f; }  // cols 256,257 pad(0)

        float4 o;
        o.x = fmaxf(fmaxf(fmaxf(a5.x, Lbuw), bu.y), fmaxf(Lm3z, m3.z)); // even
        o.y = fmaxf(fmaxf(fmaxf(a5.y, bd.x), bd.z), fmaxf(Lm3w, m3.w)); // odd
        o.z = fmaxf(fmaxf(fmaxf(a5.z, bu.y), bu.w), fmaxf(m3.x, Rm3x)); // even
        o.w = fmaxf(fmaxf(fmaxf(a5.w, bd.z), Rbdx), fmaxf(m3.y, Rm3y)); // odd
        return o;
    };

    // 6-row register window: r0..r5 = rows h-2 .. h+3
    float4 r0 = load_row(h0 - 2);
    float4 r1 = load_row(h0 - 1);
    float4 r2 = load_row(h0);
    float4 r3 = load_row(h0 + 1);
    float4 r4 = load_row(h0 + 2);
    float4 r5 = load_row(h0 + 3);

    for (int h = h0; h < h0 + ROWS_PER_WAVE; h += 2) {
        // double prefetch: rows h+4, h+5 (two loads in flight per wave)
        float4 n0 = make_float4(0.f, 0.f, 0.f, 0.f);
        float4 n1 = n0;
        if (h + 2 < h0 + ROWS_PER_WAVE) {   // skip past-halo reads on last iter
            n0 = load_row(h + 4);
            n1 = load_row(h + 5);
        }

        const float4 oa = hexrow(r0, r1, r2, r3, r4);
        const float4 ob = hexrow(r1, r2, r3, r4, r5);

        const v4f va = {oa.x, oa.y, oa.z, oa.w};
        const v4f vb = {ob.x, ob.y, ob.z, ob.w};
        __builtin_nontemporal_store(va, reinterpret_cast<v4f*>(q + (size_t)h * IMG_W + col));
        __builtin_nontemporal_store(vb, reinterpret_cast<v4f*>(q + (size_t)(h + 1) * IMG_W + col));

        // slide window by 2
        r0 = r2; r1 = r3; r2 = r4; r3 = r5; r4 = n0; r5 = n1;
    }
}

extern "C" void kernel_launch(void* const* d_in, const int* in_sizes, int n_in,
                              void* d_out, int out_size, void* d_ws, size_t ws_size,
                              hipStream_t stream) {
    (void)in_sizes; (void)n_in; (void)d_ws; (void)ws_size; (void)out_size;
    const float* in = (const float*)d_in[0];
    float* out = (float*)d_out;
    hex_maxpool_kernel<<<N_IMG * STRIPS / 4, 256, 0, stream>>>(in, out);
}

// Round 3
// 443.065 us; speedup vs baseline: 1.0200x; 1.0200x over previous
//
#include <hip/hip_runtime.h>

#define IMG_H 256
#define IMG_W 256
#define ROWS_PER_WAVE 32
#define STRIPS 8   // IMG_H / ROWS_PER_WAVE
#define N_IMG 1024 // 16*64

__device__ __forceinline__ float4 fmax4(const float4 a, const float4 b) {
    return make_float4(fmaxf(a.x, b.x), fmaxf(a.y, b.y), fmaxf(a.z, b.z), fmaxf(a.w, b.w));
}

// Fused hex maxpool: out[h][w] = max over hex window (19 taps), OOB -> 0.0
// w even: col w rows h-2..h+2 ; cols w+-1 rows h-2..h+1 ; cols w+-2 rows h-1..h+1
// w odd : col w rows h-2..h+2 ; cols w+-1 rows h-1..h+2 ; cols w+-2 rows h-1..h+1
__global__ __launch_bounds__(256, 8) void hex_maxpool_kernel(const float* __restrict__ in,
                                                             float* __restrict__ out) {
    const int lane  = threadIdx.x & 63;
    const int wave  = threadIdx.x >> 6;
    const int gw    = blockIdx.x * 4 + wave;      // global wave id, 0..8191
    const int img   = gw >> 3;                    // 0..1023
    const int strip = gw & 7;                     // 0..7
    const int h0    = strip * ROWS_PER_WAVE;
    const int col   = lane * 4;                   // 64 lanes * 4 = 256 = full row

    const float* p = in  + (size_t)img * (IMG_H * IMG_W);
    float*       q = out + (size_t)img * (IMG_H * IMG_W);

    auto load_row = [&](int r) -> float4 {
        if ((unsigned)r < (unsigned)IMG_H) {
            return *reinterpret_cast<const float4*>(p + r * IMG_W + col);
        }
        return make_float4(0.f, 0.f, 0.f, 0.f);
    };

    // one output row from its 5 input rows (h-2..h+2)
    auto hexrow = [&](const float4 w0, const float4 w1, const float4 w2,
                      const float4 w3, const float4 w4) -> float4 {
        const float4 m3 = fmax4(fmax4(w1, w2), w3); // rows h-1..h+1
        const float4 bu = fmax4(m3, w0);            // rows h-2..h+1
        const float4 bd = fmax4(m3, w4);            // rows h-1..h+2
        const float4 a5 = fmax4(bu, w4);            // rows h-2..h+2

        float Lbuw = __shfl_up(bu.w, 1);
        float Lm3z = __shfl_up(m3.z, 1);
        float Lm3w = __shfl_up(m3.w, 1);
        float Rbdx = __shfl_down(bd.x, 1);
        float Rm3x = __shfl_down(m3.x, 1);
        float Rm3y = __shfl_down(m3.y, 1);
        if (lane == 0)  { Lbuw = 0.f; Lm3z = 0.f; Lm3w = 0.f; }  // cols -1,-2 pad(0)
        if (lane == 63) { Rbdx = 0.f; Rm3x = 0.f; Rm3y = 0.f; }  // cols 256,257 pad(0)

        float4 o;
        o.x = fmaxf(fmaxf(fmaxf(a5.x, Lbuw), bu.y), fmaxf(Lm3z, m3.z)); // even
        o.y = fmaxf(fmaxf(fmaxf(a5.y, bd.x), bd.z), fmaxf(Lm3w, m3.w)); // odd
        o.z = fmaxf(fmaxf(fmaxf(a5.z, bu.y), bu.w), fmaxf(m3.x, Rm3x)); // even
        o.w = fmaxf(fmaxf(fmaxf(a5.w, bd.z), Rbdx), fmaxf(m3.y, Rm3y)); // odd
        return o;
    };

    // Software pipeline, prefetch distance 2 (4 loads in flight/wave).
    // Window r0..r5 = rows h-2..h+3; pn0,pn1 = rows h+4,h+5 (issued last iter);
    // f0,f1 = rows h+6,h+7 (issued this iter, used in 2 iters).
    float4 r0 = load_row(h0 - 2);
    float4 r1 = load_row(h0 - 1);
    float4 r2 = load_row(h0);
    float4 r3 = load_row(h0 + 1);
    float4 r4 = load_row(h0 + 2);
    float4 r5 = load_row(h0 + 3);
    float4 pn0 = load_row(h0 + 4);
    float4 pn1 = load_row(h0 + 5);

    for (int h = h0; h < h0 + ROWS_PER_WAVE; h += 2) {
        // issue loads for rows h+6, h+7 (completed 2 iterations from now)
        const float4 f0 = load_row(h + 6);
        const float4 f1 = load_row(h + 7);

        const float4 oa = hexrow(r0, r1, r2, r3, r4);
        const float4 ob = hexrow(r1, r2, r3, r4, r5);

        *reinterpret_cast<float4*>(q + (size_t)h * IMG_W + col)       = oa;
        *reinterpret_cast<float4*>(q + (size_t)(h + 1) * IMG_W + col) = ob;

        // slide window by 2
        r0 = r2; r1 = r3; r2 = r4; r3 = r5;
        r4 = pn0; r5 = pn1;        // waits on loads issued LAST iteration
        pn0 = f0; pn1 = f1;        // this iteration's loads stay in flight
    }
}

extern "C" void kernel_launch(void* const* d_in, const int* in_sizes, int n_in,
                              void* d_out, int out_size, void* d_ws, size_t ws_size,
                              hipStream_t stream) {
    (void)in_sizes; (void)n_in; (void)d_ws; (void)ws_size; (void)out_size;
    const float* in = (const float*)d_in[0];
    float* out = (float*)d_out;
    // 1024 images * 8 strips = 8192 waves = 2048 blocks of 4 waves
    hex_maxpool_kernel<<<N_IMG * STRIPS / 4, 256, 0, stream>>>(in, out);
}

// Round 4
// 425.602 us; speedup vs baseline: 1.0618x; 1.0410x over previous
//
#include <hip/hip_runtime.h>
#include <stdint.h>

#define IMG_H 256
#define IMG_W 256
#define STRIP_ROWS 16            // output rows per block
#define LDS_ROWS   20            // STRIP_ROWS + 4 halo rows
#define STRIPS_PER_IMG 16        // IMG_H / STRIP_ROWS
#define N_IMG 1024               // 16*64

__device__ __forceinline__ float4 fmax4(const float4 a, const float4 b) {
    return make_float4(fmaxf(a.x, b.x), fmaxf(a.y, b.y), fmaxf(a.z, b.z), fmaxf(a.w, b.w));
}

// Fused hex maxpool: out[h][w] = max over 19-tap hex window, OOB -> 0.0
// w even: col w rows h-2..h+2 ; cols w+-1 rows h-2..h+1 ; cols w+-2 rows h-1..h+1
// w odd : col w rows h-2..h+2 ; cols w+-1 rows h-1..h+2 ; cols w+-2 rows h-1..h+1
__global__ __launch_bounds__(256) void hex_maxpool_kernel(const float* __restrict__ in,
                                                          float* __restrict__ out) {
    __shared__ float smem[LDS_ROWS * IMG_W];   // 20 KB -> 8 blocks/CU LDS-limited

    const int lane  = threadIdx.x & 63;
    const int wave  = threadIdx.x >> 6;
    const int img   = blockIdx.x >> 4;         // 16 strips per image
    const int strip = blockIdx.x & 15;
    const int S     = strip * STRIP_ROWS;      // first output row of this block

    const float* p = in  + (size_t)img * (IMG_H * IMG_W);
    float*       q = out + (size_t)img * (IMG_H * IMG_W);

    // ---- stage phase: 20 rows (S-2 .. S+17) -> LDS via async DMA ----
    // wave w stages LDS rows w*5 .. w*5+4; each global_load_lds moves one
    // full row (64 lanes x 16 B = 1 KiB), no VGPR writeback -> whole 20 KB
    // burst in flight per block.
#pragma unroll
    for (int j5 = 0; j5 < 5; ++j5) {
        const int j = wave * 5 + j5;           // LDS row index (wave-uniform)
        const int g = S - 2 + j;               // global row (wave-uniform)
        if ((unsigned)g < (unsigned)IMG_H) {
            const float* gp = p + (size_t)g * IMG_W + lane * 4;
            __builtin_amdgcn_global_load_lds(
                (const __attribute__((address_space(1))) uint32_t*)gp,
                (__attribute__((address_space(3))) uint32_t*)&smem[j * IMG_W],
                16, 0, 0);
        } else {
            // image-boundary halo row: pad with 0.0
            *reinterpret_cast<float4*>(&smem[j * IMG_W + lane * 4]) =
                make_float4(0.f, 0.f, 0.f, 0.f);
        }
    }
    __syncthreads();   // drains vmcnt (DMA) + lgkmcnt (zero-fill)

    // ---- compute phase: wave w produces output rows S+w*4 .. S+w*4+3 ----
    auto hexrow = [&](const float4 w0, const float4 w1, const float4 w2,
                      const float4 w3, const float4 w4) -> float4 {
        const float4 m3 = fmax4(fmax4(w1, w2), w3); // rows h-1..h+1
        const float4 bu = fmax4(m3, w0);            // rows h-2..h+1
        const float4 bd = fmax4(m3, w4);            // rows h-1..h+2
        const float4 a5 = fmax4(bu, w4);            // rows h-2..h+2

        float Lbuw = __shfl_up(bu.w, 1);
        float Lm3z = __shfl_up(m3.z, 1);
        float Lm3w = __shfl_up(m3.w, 1);
        float Rbdx = __shfl_down(bd.x, 1);
        float Rm3x = __shfl_down(m3.x, 1);
        float Rm3y = __shfl_down(m3.y, 1);
        if (lane == 0)  { Lbuw = 0.f; Lm3z = 0.f; Lm3w = 0.f; }  // cols -1,-2 pad(0)
        if (lane == 63) { Rbdx = 0.f; Rm3x = 0.f; Rm3y = 0.f; }  // cols 256,257 pad(0)

        float4 o;
        o.x = fmaxf(fmaxf(fmaxf(a5.x, Lbuw), bu.y), fmaxf(Lm3z, m3.z)); // even col
        o.y = fmaxf(fmaxf(fmaxf(a5.y, bd.x), bd.z), fmaxf(Lm3w, m3.w)); // odd col
        o.z = fmaxf(fmaxf(fmaxf(a5.z, bu.y), bu.w), fmaxf(m3.x, Rm3x)); // even col
        o.w = fmaxf(fmaxf(fmaxf(a5.w, bd.z), Rbdx), fmaxf(m3.y, Rm3y)); // odd col
        return o;
    };

    const int base = wave * 4;   // LDS row of (first output row - 2)
    float4 r[8];
#pragma unroll
    for (int j = 0; j < 8; ++j) {
        r[j] = *reinterpret_cast<const float4*>(&smem[(base + j) * IMG_W + lane * 4]);
    }

#pragma unroll
    for (int k = 0; k < 4; ++k) {
        const float4 o = hexrow(r[k], r[k + 1], r[k + 2], r[k + 3], r[k + 4]);
        *reinterpret_cast<float4*>(q + (size_t)(S + base + k) * IMG_W + lane * 4) = o;
    }
}

extern "C" void kernel_launch(void* const* d_in, const int* in_sizes, int n_in,
                              void* d_out, int out_size, void* d_ws, size_t ws_size,
                              hipStream_t stream) {
    (void)in_sizes; (void)n_in; (void)d_ws; (void)ws_size; (void)out_size;
    const float* in = (const float*)d_in[0];
    float* out = (float*)d_out;
    // 1024 images * 16 strips = 16384 blocks of 256 threads (4 waves)
    hex_maxpool_kernel<<<N_IMG * STRIPS_PER_IMG, 256, 0, stream>>>(in, out);
}